// Round 2
// baseline (274.940 us; speedup 1.0000x reference)
//
#include <hip/hip_runtime.h>

#define HW 50176            // 224*224
#define TT 64
#define NB1 1176            // pass1 blocks; 1176*256 = 301056 = 6*HW threads
#define S1 4                // strips per thread in pass1 (6*HW*4 = 24*HW = B*C*HW)
#define NB2 1568            // pass2 blocks; 1568*256 = 401408 = 8*HW pixels exactly

__device__ __forceinline__ float gelu_sig(float x) {
    // x * sigmoid(1.702 x); only used for the min/max pass (error cancels in normalize)
    return x / (1.0f + exp2f(-2.4554669f * x));
}
__device__ __forceinline__ float gelu_erf(float x) {
    return 0.5f * x * (1.0f + erff(0.70710678f * x));
}
// order-preserving float <-> uint encoding for atomicMin/Max
__device__ __forceinline__ unsigned encf(float f) {
    unsigned u = __float_as_uint(f);
    return (u & 0x80000000u) ? ~u : (u | 0x80000000u);
}
__device__ __forceinline__ float decf(unsigned u) {
    unsigned b = (u & 0x80000000u) ? (u ^ 0x80000000u) : ~u;
    return __uint_as_float(b);
}
// packed f16 min on a uint carrier (v_pk_min_f16); avoids broken __hmin2 overload
__device__ __forceinline__ unsigned pk_min_f16(unsigned a, unsigned b) {
    unsigned r;
    asm("v_pk_min_f16 %0, %1, %2" : "=v"(r) : "v"(a), "v"(b));
    return r;
}
__device__ __forceinline__ unsigned pack2(float lo, float hi) {
    auto p = __builtin_amdgcn_cvt_pkrtz(lo, hi);   // f32x2 -> f16x2 (RTZ)
    return __builtin_bit_cast(unsigned, p);
}

__global__ void k_init(unsigned* __restrict__ g) {
    int i = threadIdx.x;           // 128 threads
    g[i] = (i < TT) ? 0xFFFFFFFFu : 0u;   // [0..63] enc-min init, [64..127] enc-max init
}

__global__ __launch_bounds__(256) void k_pass1(const float* __restrict__ x,
                                               unsigned* __restrict__ gmm) {
    __shared__ unsigned smin[TT], smax[TT];
    const int tid = threadIdx.x;
    if (tid < TT) { smin[tid] = 0xFFFFFFFFu; smax[tid] = 0u; }
    __syncthreads();

    // acc[t] = packed f16 (min g, min -g). 64 VGPRs.
    unsigned acc[TT];
    #pragma unroll
    for (int t = 0; t < TT; ++t) acc[t] = 0x7BFF7BFFu;   // (65504, 65504)

    const int gid = blockIdx.x * 256 + tid;        // < 301056 = 6*HW
    int bc = gid / HW;
    int hw = gid - bc * HW;
    const float* xp = x + (size_t)bc * (TT * (size_t)HW) + hw;

    for (int k = 0; k < S1; ++k) {                 // strip stride 6*HW (bc += 6)
        float w0 = xp[0], w1 = xp[HW], w2 = xp[2*HW], w3 = xp[3*HW], w4 = xp[4*HW];
        #pragma unroll
        for (int t = 0; t < TT; ++t) {
            float re;
            if (t < 60)       re = 4.f*(w4 - w0) + 2.f*(w3 - w1);   // weights -4,-2,0,2,4
            else if (t == 60) re = 3.f*(w3 - w0) + (w2 - w1);       // -3,-1,1,3
            else if (t == 61) re = 2.f*(w2 - w0);                   // -2,0,2
            else if (t == 62) re = w1 - w0;                         // -1,1
            else              re = 0.f;                             // weight 0
            float g = gelu_sig(re);
            acc[t] = pk_min_f16(acc[t], pack2(g, -g));
            w0 = w1; w1 = w2; w2 = w3; w3 = w4;
            if (t < 59) w4 = xp[(size_t)(t + 5) * HW];
        }
        xp += (size_t)6 * TT * HW;
    }

    const int lane = tid & 63;
    #pragma unroll
    for (int t = 0; t < TT; ++t) {
        unsigned a = acc[t];
        #pragma unroll
        for (int off = 32; off > 0; off >>= 1)
            a = pk_min_f16(a, (unsigned)__shfl_xor((int)a, off, 64));
        if (lane == 0) {
            union { unsigned u; _Float16 h[2]; } cv; cv.u = a;
            atomicMin(&smin[t], encf((float)cv.h[0]));
            atomicMax(&smax[t], encf(-(float)cv.h[1]));
        }
    }
    __syncthreads();
    if (tid < TT)            atomicMin(&gmm[tid], smin[tid]);
    else if (tid < 2 * TT)   atomicMax(&gmm[tid], smax[tid - TT]);
}

__global__ void k_consts(const unsigned* __restrict__ gmm, float* __restrict__ ab) {
    int t = threadIdx.x;                       // 64 threads
    float mn = decf(gmm[t]);
    float mx = decf(gmm[TT + t]) - mn;         // max after min-subtract
    float inv = 1.0f / ((mx != 0.0f) ? mx : 1e-5f);
    ab[t]      = inv;                                            // A[t]
    ab[TT + t] = -mn * (0.2989f + 0.587f + 0.114f) * inv;        // B[t]
}

__global__ __launch_bounds__(256) void k_pass2(const float* __restrict__ x,
                                               const float* __restrict__ ab,
                                               float* __restrict__ out) {
    __shared__ float sA[TT], sB[TT];
    const int tid = threadIdx.x;
    if (tid < TT)          sA[tid] = ab[tid];
    else if (tid < 2 * TT) sB[tid - TT] = ab[tid];
    __syncthreads();

    const int pix = blockIdx.x * 256 + tid;    // < 401408 = 8*HW
    const int b  = pix / HW;
    const int hw = pix - b * HW;
    const float* x0 = x + (size_t)(b * 3) * (TT * (size_t)HW) + hw;
    const float* x1 = x0 + (size_t)TT * HW;
    const float* x2 = x1 + (size_t)TT * HW;
    float* op = out + (size_t)b * (68 * (size_t)HW) + hw;

    // leading mask frames
    op[0] = 0.f; op[HW] = 0.f; op[2 * (size_t)HW] = 0.f; op[3 * (size_t)HW] = 0.f;
    op += 4 * (size_t)HW;                      // op[t*HW] = output frame t+4

    float a0 = x0[0], a1 = x0[HW], a2 = x0[2*HW], a3 = x0[3*HW], a4 = x0[4*HW];
    float b0 = x1[0], b1 = x1[HW], b2 = x1[2*HW], b3 = x1[3*HW], b4 = x1[4*HW];
    float c0 = x2[0], c1 = x2[HW], c2 = x2[2*HW], c3 = x2[3*HW], c4 = x2[4*HW];

    auto emit = [&](int t, float ra, float rb, float rc) {
        float gs = 0.2989f * gelu_erf(ra) + 0.587f * gelu_erf(rb) + 0.114f * gelu_erf(rc);
        op[(size_t)t * HW] = fmaf(gs, sA[t], sB[t]);
    };

    for (int t = 0; t < 59; ++t) {
        emit(t, 4.f*(a4-a0) + 2.f*(a3-a1),
                4.f*(b4-b0) + 2.f*(b3-b1),
                4.f*(c4-c0) + 2.f*(c3-c1));
        a0=a1; a1=a2; a2=a3; a3=a4; a4 = x0[(size_t)(t+5)*HW];
        b0=b1; b1=b2; b2=b3; b3=b4; b4 = x1[(size_t)(t+5)*HW];
        c0=c1; c1=c2; c2=c3; c3=c4; c4 = x2[(size_t)(t+5)*HW];
    }
    // t = 59 (full window, frames 59..63 in regs)
    emit(59, 4.f*(a4-a0) + 2.f*(a3-a1),
             4.f*(b4-b0) + 2.f*(b3-b1),
             4.f*(c4-c0) + 2.f*(c3-c1));
    a0=a1; a1=a2; a2=a3; a3=a4;
    b0=b1; b1=b2; b2=b3; b3=b4;
    c0=c1; c1=c2; c2=c3; c3=c4;
    // t = 60 (frames 60..63 in w0..w3)
    emit(60, 3.f*(a3-a0) + (a2-a1),
             3.f*(b3-b0) + (b2-b1),
             3.f*(c3-c0) + (c2-c1));
    a0=a1; a1=a2; a2=a3;
    b0=b1; b1=b2; b2=b3;
    c0=c1; c1=c2; c2=c3;
    // t = 61 (frames 61..63 in w0..w2)
    emit(61, 2.f*(a2-a0), 2.f*(b2-b0), 2.f*(c2-c0));
    a0=a1; a1=a2;
    b0=b1; b1=b2;
    c0=c1; c1=c2;
    // t = 62 (frames 62..63 in w0..w1)
    emit(62, a1-a0, b1-b0, c1-c0);
    // t = 63: re == 0 -> gelu 0 -> out = B[63] (== 0 since mn[63] == 0)
    op[63 * (size_t)HW] = sB[63];
}

extern "C" void kernel_launch(void* const* d_in, const int* in_sizes, int n_in,
                              void* d_out, int out_size, void* d_ws, size_t ws_size,
                              hipStream_t stream) {
    const float* x = (const float*)d_in[0];
    float* out = (float*)d_out;
    unsigned* gmm = (unsigned*)d_ws;           // 128 x u32: enc-min[64], enc-max[64]
    float* ab = (float*)d_ws + 128;            // 128 x f32: A[64], B[64]

    k_init  <<<1,   128, 0, stream>>>(gmm);
    k_pass1 <<<NB1, 256, 0, stream>>>(x, gmm);
    k_consts<<<1,    64, 0, stream>>>(gmm, ab);
    k_pass2 <<<NB2, 256, 0, stream>>>(x, ab, out);
}

// Round 3
// 196.462 us; speedup vs baseline: 1.3995x; 1.3995x over previous
//
#include <hip/hip_runtime.h>

#define HW 50176            // 224*224
#define TT 64
#define NB1 1176            // pass1 blocks; 1176*256 threads * 4 px = 24*HW strips
#define NB2 1568            // pass2 blocks; 1568*256 = 401408 = 8*HW pixels exactly

__device__ __forceinline__ float gelu_erf(float x) {
    return 0.5f * x * (1.0f + erff(0.70710678f * x));
}
// order-preserving float <-> uint encoding for atomicMin/Max
__device__ __forceinline__ unsigned encf(float f) {
    unsigned u = __float_as_uint(f);
    return (u & 0x80000000u) ? ~u : (u | 0x80000000u);
}
__device__ __forceinline__ float decf(unsigned u) {
    unsigned b = (u & 0x80000000u) ? (u ^ 0x80000000u) : ~u;
    return __uint_as_float(b);
}
// packed f16 min on a uint carrier (v_pk_min_f16)
__device__ __forceinline__ unsigned pk_min_f16(unsigned a, unsigned b) {
    unsigned r;
    asm("v_pk_min_f16 %0, %1, %2" : "=v"(r) : "v"(a), "v"(b));
    return r;
}
__device__ __forceinline__ unsigned pack2(float lo, float hi) {
    auto p = __builtin_amdgcn_cvt_pkrtz(lo, hi);   // f32x2 -> f16x2 (RTZ)
    return __builtin_bit_cast(unsigned, p);
}

__global__ void k_init(unsigned* __restrict__ g) {
    int i = threadIdx.x;           // 128 threads
    g[i] = (i < TT) ? 0xFFFFFFFFu : 0u;   // [0..63] enc-min init, [64..127] enc-max init
}

// Pass 1: track packed-f16 (min re, min -re) per t; gelu applied only at the tail.
__global__ __launch_bounds__(256, 4) void k_pass1(const float* __restrict__ x,
                                                  unsigned* __restrict__ gmm) {
    __shared__ unsigned smin[TT], smax[TT];
    const int tid = threadIdx.x;
    if (tid < TT) { smin[tid] = 0xFFFFFFFFu; smax[tid] = 0u; }
    __syncthreads();

    unsigned acc[TT];
    #pragma unroll
    for (int t = 0; t < TT; ++t) acc[t] = 0x7BFF7BFFu;   // (65504, 65504)

    const int gid = blockIdx.x * 256 + tid;     // < 301056 = 24*HW/4
    const int bc  = gid / (HW / 4);             // 0..23  (b*3+c)
    const int hw  = (gid - bc * (HW / 4)) * 4;
    const float* xp = x + (size_t)bc * (TT * (size_t)HW) + hw;

    #define LD(f) (*(const float4*)(xp + (size_t)(f) * HW))
    float4 w0 = LD(0), w1 = LD(1), w2 = LD(2), w3 = LD(3), w4 = LD(4);
    float4 p0 = LD(5), p1 = LD(6);              // 2-frame prefetch pipeline

    #pragma unroll
    for (int t = 0; t < TT; ++t) {
        float4 re;
        if (t < 60) {
            re.x = 4.f*(w4.x-w0.x) + 2.f*(w3.x-w1.x);
            re.y = 4.f*(w4.y-w0.y) + 2.f*(w3.y-w1.y);
            re.z = 4.f*(w4.z-w0.z) + 2.f*(w3.z-w1.z);
            re.w = 4.f*(w4.w-w0.w) + 2.f*(w3.w-w1.w);
        } else if (t == 60) {
            re.x = 3.f*(w3.x-w0.x) + (w2.x-w1.x);
            re.y = 3.f*(w3.y-w0.y) + (w2.y-w1.y);
            re.z = 3.f*(w3.z-w0.z) + (w2.z-w1.z);
            re.w = 3.f*(w3.w-w0.w) + (w2.w-w1.w);
        } else if (t == 61) {
            re.x = 2.f*(w2.x-w0.x); re.y = 2.f*(w2.y-w0.y);
            re.z = 2.f*(w2.z-w0.z); re.w = 2.f*(w2.w-w0.w);
        } else if (t == 62) {
            re.x = w1.x-w0.x; re.y = w1.y-w0.y;
            re.z = w1.z-w0.z; re.w = w1.w-w0.w;
        } else {
            re.x = re.y = re.z = re.w = 0.f;
        }
        unsigned m = pk_min_f16(pk_min_f16(pack2(re.x, -re.x), pack2(re.y, -re.y)),
                                pk_min_f16(pack2(re.z, -re.z), pack2(re.w, -re.w)));
        acc[t] = pk_min_f16(acc[t], m);
        w0 = w1; w1 = w2; w2 = w3; w3 = w4; w4 = p0; p0 = p1;
        if (t < 57) p1 = LD(t + 7);
    }
    #undef LD

    // wave-level butterfly reduce; lane L keeps the reduced value for t == L
    const int lane = tid & 63;
    unsigned keep = 0x7BFF7BFFu;
    #pragma unroll
    for (int t = 0; t < TT; ++t) {
        unsigned a = acc[t];
        #pragma unroll
        for (int off = 32; off; off >>= 1)
            a = pk_min_f16(a, (unsigned)__shfl_xor((int)a, off, 64));
        if (lane == t) keep = a;
    }

    // exact erf-gelu applied only here (2 per lane)
    union { unsigned u; _Float16 h[2]; } cv; cv.u = keep;
    const float amin = (float)cv.h[0];
    const float amax = -(float)cv.h[1];
    const float g0 = gelu_erf(amin), g1 = gelu_erf(amax);
    const float gmax = fmaxf(g0, g1);
    const float XSTAR = -0.7517916f;             // argmin of gelu
    float gmin;
    if (amin >= XSTAR)      gmin = g0;           // gelu increasing on [x*,inf)
    else if (amax <= XSTAR) gmin = g1;           // gelu decreasing on (-inf,x*]
    else                    gmin = fminf(gelu_erf(XSTAR), fminf(g0, g1)); // bracketed dip
    atomicMin(&smin[lane], encf(gmin));
    atomicMax(&smax[lane], encf(gmax));
    __syncthreads();
    if (tid < TT)            atomicMin(&gmm[tid], smin[tid]);
    else if (tid < 2 * TT)   atomicMax(&gmm[tid], smax[tid - TT]);
}

__global__ void k_consts(const unsigned* __restrict__ gmm, float* __restrict__ ab) {
    int t = threadIdx.x;                       // 64 threads
    float mn = decf(gmm[t]);
    float mx = decf(gmm[TT + t]) - mn;         // max after min-subtract
    float inv = 1.0f / ((mx != 0.0f) ? mx : 1e-5f);
    ab[t]      = inv;                                            // A[t]
    ab[TT + t] = -mn * (0.2989f + 0.587f + 0.114f) * inv;        // B[t]
}

__global__ __launch_bounds__(256) void k_pass2(const float* __restrict__ x,
                                               const float* __restrict__ ab,
                                               float* __restrict__ out) {
    __shared__ float sA[TT], sB[TT];
    const int tid = threadIdx.x;
    if (tid < TT)          sA[tid] = ab[tid];
    else if (tid < 2 * TT) sB[tid - TT] = ab[tid];
    __syncthreads();

    const int pix = blockIdx.x * 256 + tid;    // < 401408 = 8*HW
    const int b  = pix / HW;
    const int hw = pix - b * HW;
    const float* x0 = x + (size_t)(b * 3) * (TT * (size_t)HW) + hw;
    const float* x1 = x0 + (size_t)TT * HW;
    const float* x2 = x1 + (size_t)TT * HW;
    float* op = out + (size_t)b * (68 * (size_t)HW) + hw;

    // leading mask frames
    op[0] = 0.f; op[HW] = 0.f; op[2 * (size_t)HW] = 0.f; op[3 * (size_t)HW] = 0.f;
    op += 4 * (size_t)HW;                      // op[t*HW] = output frame t+4

    float a0 = x0[0], a1 = x0[HW], a2 = x0[2*HW], a3 = x0[3*HW], a4 = x0[4*HW];
    float b0 = x1[0], b1 = x1[HW], b2 = x1[2*HW], b3 = x1[3*HW], b4 = x1[4*HW];
    float c0 = x2[0], c1 = x2[HW], c2 = x2[2*HW], c3 = x2[3*HW], c4 = x2[4*HW];

    auto emit = [&](int t, float ra, float rb, float rc) {
        float gs = 0.2989f * gelu_erf(ra) + 0.587f * gelu_erf(rb) + 0.114f * gelu_erf(rc);
        op[(size_t)t * HW] = fmaf(gs, sA[t], sB[t]);
    };

    for (int t = 0; t < 59; ++t) {
        emit(t, 4.f*(a4-a0) + 2.f*(a3-a1),
                4.f*(b4-b0) + 2.f*(b3-b1),
                4.f*(c4-c0) + 2.f*(c3-c1));
        a0=a1; a1=a2; a2=a3; a3=a4; a4 = x0[(size_t)(t+5)*HW];
        b0=b1; b1=b2; b2=b3; b3=b4; b4 = x1[(size_t)(t+5)*HW];
        c0=c1; c1=c2; c2=c3; c3=c4; c4 = x2[(size_t)(t+5)*HW];
    }
    emit(59, 4.f*(a4-a0) + 2.f*(a3-a1),
             4.f*(b4-b0) + 2.f*(b3-b1),
             4.f*(c4-c0) + 2.f*(c3-c1));
    a0=a1; a1=a2; a2=a3; a3=a4;
    b0=b1; b1=b2; b2=b3; b3=b4;
    c0=c1; c1=c2; c2=c3; c3=c4;
    emit(60, 3.f*(a3-a0) + (a2-a1),
             3.f*(b3-b0) + (b2-b1),
             3.f*(c3-c0) + (c2-c1));
    a0=a1; a1=a2; a2=a3;
    b0=b1; b1=b2; b2=b3;
    c0=c1; c1=c2; c2=c3;
    emit(61, 2.f*(a2-a0), 2.f*(b2-b0), 2.f*(c2-c0));
    a0=a1; a1=a2;
    b0=b1; b1=b2;
    c0=c1; c1=c2;
    emit(62, a1-a0, b1-b0, c1-c0);
    // t = 63: re == 0 -> gelu 0 -> out = B[63] (== 0 since mn[63] == 0)
    op[63 * (size_t)HW] = sB[63];
}

extern "C" void kernel_launch(void* const* d_in, const int* in_sizes, int n_in,
                              void* d_out, int out_size, void* d_ws, size_t ws_size,
                              hipStream_t stream) {
    const float* x = (const float*)d_in[0];
    float* out = (float*)d_out;
    unsigned* gmm = (unsigned*)d_ws;           // 128 x u32: enc-min[64], enc-max[64]
    float* ab = (float*)d_ws + 128;            // 128 x f32: A[64], B[64]

    k_init  <<<1,   128, 0, stream>>>(gmm);
    k_pass1 <<<NB1, 256, 0, stream>>>(x, gmm);
    k_consts<<<1,    64, 0, stream>>>(gmm, ab);
    k_pass2 <<<NB2, 256, 0, stream>>>(x, ab, out);
}

// Round 4
// 170.162 us; speedup vs baseline: 1.6158x; 1.1546x over previous
//
#include <hip/hip_runtime.h>

#define HW 50176            // 224*224
#define TT 64
#define NB1 4704            // 24 bc-strips × 4 t-chunks × 49 hw-blocks (49*256*4 = HW)
#define NB2 1568            // pass2: 1568*256 = 401408 = 8*HW pixels exactly

__device__ __forceinline__ float gelu_erf(float x) {
    return 0.5f * x * (1.0f + erff(0.70710678f * x));
}
// order-preserving float <-> uint encoding for atomicMin/Max
__device__ __forceinline__ unsigned encf(float f) {
    unsigned u = __float_as_uint(f);
    return (u & 0x80000000u) ? ~u : (u | 0x80000000u);
}
__device__ __forceinline__ float decf(unsigned u) {
    unsigned b = (u & 0x80000000u) ? (u ^ 0x80000000u) : ~u;
    return __uint_as_float(b);
}
// packed f16 min on a uint carrier (v_pk_min_f16)
__device__ __forceinline__ unsigned pk_min_f16(unsigned a, unsigned b) {
    unsigned r;
    asm("v_pk_min_f16 %0, %1, %2" : "=v"(r) : "v"(a), "v"(b));
    return r;
}
__device__ __forceinline__ unsigned pack2(float lo, float hi) {
    auto p = __builtin_amdgcn_cvt_pkrtz(lo, hi);   // f32x2 -> f16x2 (RTZ)
    return __builtin_bit_cast(unsigned, p);
}
__device__ __forceinline__ unsigned min4(float4 re) {
    return pk_min_f16(pk_min_f16(pack2(re.x, -re.x), pack2(re.y, -re.y)),
                      pk_min_f16(pack2(re.z, -re.z), pack2(re.w, -re.w)));
}

__global__ void k_init(unsigned* __restrict__ g) {
    int i = threadIdx.x;           // 128 threads
    g[i] = (i < TT) ? 0xFFFFFFFFu : 0u;   // enc-min init / enc-max init
}

// Pass 1: per-thread 16-window t-chunk, packed-f16 (min re, min -re) per t.
__global__ __launch_bounds__(256, 6) void k_pass1(const float* __restrict__ x,
                                                  unsigned* __restrict__ gmm) {
    __shared__ unsigned smin[16], smax[16];
    const int tid = threadIdx.x;
    if (tid < 16) { smin[tid] = 0xFFFFFFFFu; smax[tid] = 0u; }
    __syncthreads();

    const int bid   = blockIdx.x;
    const int bc    = bid / 196;           // 0..23  (b*3+c)
    const int rem   = bid - bc * 196;
    const int tc    = rem / 49;            // t-chunk 0..3
    const int hwblk = rem - tc * 49;
    const int t0    = tc * 16;
    const int hw    = (hwblk * 256 + tid) * 4;
    const float* xq = x + (size_t)bc * (TT * (size_t)HW) + (size_t)t0 * HW + hw;

    unsigned acc[16];
    #pragma unroll
    for (int j = 0; j < 16; ++j) acc[j] = 0x7BFF7BFFu;   // (65504, 65504)

    #define LD(f) (*(const float4*)(xq + (size_t)(f) * HW))
    float4 w0 = LD(0), w1 = LD(1), w2 = LD(2), w3 = LD(3), w4 = LD(4);
    float4 p0 = LD(5), p1 = LD(6);

    if (tc < 3) {
        #pragma unroll
        for (int j = 0; j < 16; ++j) {     // windows t0+j, all full-weight
            float4 re;
            re.x = 4.f*(w4.x-w0.x) + 2.f*(w3.x-w1.x);
            re.y = 4.f*(w4.y-w0.y) + 2.f*(w3.y-w1.y);
            re.z = 4.f*(w4.z-w0.z) + 2.f*(w3.z-w1.z);
            re.w = 4.f*(w4.w-w0.w) + 2.f*(w3.w-w1.w);
            acc[j] = pk_min_f16(acc[j], min4(re));
            w0 = w1; w1 = w2; w2 = w3; w3 = w4; w4 = p0; p0 = p1;
            if (j < 13) p1 = LD(j + 7);    // frames up to rel 19
        }
    } else {
        #pragma unroll
        for (int j = 0; j < 16; ++j) {     // windows 48+j; tails at 60..63
            float4 re;
            if (j < 12) {
                re.x = 4.f*(w4.x-w0.x) + 2.f*(w3.x-w1.x);
                re.y = 4.f*(w4.y-w0.y) + 2.f*(w3.y-w1.y);
                re.z = 4.f*(w4.z-w0.z) + 2.f*(w3.z-w1.z);
                re.w = 4.f*(w4.w-w0.w) + 2.f*(w3.w-w1.w);
            } else if (j == 12) {          // t=60: weights -3,-1,1,3
                re.x = 3.f*(w3.x-w0.x) + (w2.x-w1.x);
                re.y = 3.f*(w3.y-w0.y) + (w2.y-w1.y);
                re.z = 3.f*(w3.z-w0.z) + (w2.z-w1.z);
                re.w = 3.f*(w3.w-w0.w) + (w2.w-w1.w);
            } else if (j == 13) {          // t=61: -2,0,2
                re.x = 2.f*(w2.x-w0.x); re.y = 2.f*(w2.y-w0.y);
                re.z = 2.f*(w2.z-w0.z); re.w = 2.f*(w2.w-w0.w);
            } else if (j == 14) {          // t=62: -1,1
                re.x = w1.x-w0.x; re.y = w1.y-w0.y;
                re.z = w1.z-w0.z; re.w = w1.w-w0.w;
            } else {                       // t=63: weight 0
                re.x = re.y = re.z = re.w = 0.f;
            }
            acc[j] = pk_min_f16(acc[j], min4(re));
            w0 = w1; w1 = w2; w2 = w3; w3 = w4; w4 = p0; p0 = p1;
            if (j < 9) p1 = LD(j + 7);     // frames up to rel 15 (abs 63)
        }
    }
    #undef LD

    // wave butterfly reduce; lane j keeps window t0+j
    const int lane = tid & 63;
    unsigned keep = 0x7BFF7BFFu;
    #pragma unroll
    for (int j = 0; j < 16; ++j) {
        unsigned a = acc[j];
        #pragma unroll
        for (int off = 32; off; off >>= 1)
            a = pk_min_f16(a, (unsigned)__shfl_xor((int)a, off, 64));
        if (lane == j) keep = a;
    }

    if (lane < 16) {
        union { unsigned u; _Float16 h[2]; } cv; cv.u = keep;
        const float amin = (float)cv.h[0];
        const float amax = -(float)cv.h[1];
        const float g0 = gelu_erf(amin), g1 = gelu_erf(amax);
        const float gmax = fmaxf(g0, g1);
        const float XSTAR = -0.7517916f;             // argmin of gelu
        float gmin;
        if (amin >= XSTAR)      gmin = g0;
        else if (amax <= XSTAR) gmin = g1;
        else                    gmin = fminf(gelu_erf(XSTAR), fminf(g0, g1));
        atomicMin(&smin[lane], encf(gmin));
        atomicMax(&smax[lane], encf(gmax));
    }
    __syncthreads();
    if (tid < 16)            atomicMin(&gmm[t0 + tid], smin[tid]);
    else if (tid < 32)       atomicMax(&gmm[TT + t0 + tid - 16], smax[tid - 16]);
}

__global__ void k_consts(const unsigned* __restrict__ gmm, float* __restrict__ ab) {
    int t = threadIdx.x;                       // 64 threads
    float mn = decf(gmm[t]);
    float mx = decf(gmm[TT + t]) - mn;         // max after min-subtract
    float inv = 1.0f / ((mx != 0.0f) ? mx : 1e-5f);
    ab[t]      = inv;                                            // A[t]
    ab[TT + t] = -mn * (0.2989f + 0.587f + 0.114f) * inv;        // B[t]
}

__global__ __launch_bounds__(256) void k_pass2(const float* __restrict__ x,
                                               const float* __restrict__ ab,
                                               float* __restrict__ out) {
    __shared__ float sA[TT], sB[TT];
    const int tid = threadIdx.x;
    if (tid < TT)          sA[tid] = ab[tid];
    else if (tid < 2 * TT) sB[tid - TT] = ab[tid];
    __syncthreads();

    const int pix = blockIdx.x * 256 + tid;    // < 401408 = 8*HW
    const int b  = pix / HW;
    const int hw = pix - b * HW;
    const float* x0 = x + (size_t)(b * 3) * (TT * (size_t)HW) + hw;
    const float* x1 = x0 + (size_t)TT * HW;
    const float* x2 = x1 + (size_t)TT * HW;
    float* op = out + (size_t)b * (68 * (size_t)HW) + hw;

    // leading mask frames
    op[0] = 0.f; op[HW] = 0.f; op[2 * (size_t)HW] = 0.f; op[3 * (size_t)HW] = 0.f;
    op += 4 * (size_t)HW;                      // op[t*HW] = output frame t+4

    float a0 = x0[0], a1 = x0[HW], a2 = x0[2*HW], a3 = x0[3*HW], a4 = x0[4*HW];
    float b0 = x1[0], b1 = x1[HW], b2 = x1[2*HW], b3 = x1[3*HW], b4 = x1[4*HW];
    float c0 = x2[0], c1 = x2[HW], c2 = x2[2*HW], c3 = x2[3*HW], c4 = x2[4*HW];

    auto emit = [&](int t, float ra, float rb, float rc) {
        float gs = 0.2989f * gelu_erf(ra) + 0.587f * gelu_erf(rb) + 0.114f * gelu_erf(rc);
        op[(size_t)t * HW] = fmaf(gs, sA[t], sB[t]);
    };

    for (int t = 0; t < 59; ++t) {
        emit(t, 4.f*(a4-a0) + 2.f*(a3-a1),
                4.f*(b4-b0) + 2.f*(b3-b1),
                4.f*(c4-c0) + 2.f*(c3-c1));
        a0=a1; a1=a2; a2=a3; a3=a4; a4 = x0[(size_t)(t+5)*HW];
        b0=b1; b1=b2; b2=b3; b3=b4; b4 = x1[(size_t)(t+5)*HW];
        c0=c1; c1=c2; c2=c3; c3=c4; c4 = x2[(size_t)(t+5)*HW];
    }
    emit(59, 4.f*(a4-a0) + 2.f*(a3-a1),
             4.f*(b4-b0) + 2.f*(b3-b1),
             4.f*(c4-c0) + 2.f*(c3-c1));
    a0=a1; a1=a2; a2=a3; a3=a4;
    b0=b1; b1=b2; b2=b3; b3=b4;
    c0=c1; c1=c2; c2=c3; c3=c4;
    emit(60, 3.f*(a3-a0) + (a2-a1),
             3.f*(b3-b0) + (b2-b1),
             3.f*(c3-c0) + (c2-c1));
    a0=a1; a1=a2; a2=a3;
    b0=b1; b1=b2; b2=b3;
    c0=c1; c1=c2; c2=c3;
    emit(61, 2.f*(a2-a0), 2.f*(b2-b0), 2.f*(c2-c0));
    a0=a1; a1=a2;
    b0=b1; b1=b2;
    c0=c1; c1=c2;
    emit(62, a1-a0, b1-b0, c1-c0);
    // t = 63: re == 0 -> gelu 0 -> out = B[63] (== 0 since mn[63] == 0)
    op[63 * (size_t)HW] = sB[63];
}

extern "C" void kernel_launch(void* const* d_in, const int* in_sizes, int n_in,
                              void* d_out, int out_size, void* d_ws, size_t ws_size,
                              hipStream_t stream) {
    const float* x = (const float*)d_in[0];
    float* out = (float*)d_out;
    unsigned* gmm = (unsigned*)d_ws;           // 128 x u32: enc-min[64], enc-max[64]
    float* ab = (float*)d_ws + 128;            // 128 x f32: A[64], B[64]

    k_init  <<<1,   128, 0, stream>>>(gmm);
    k_pass1 <<<NB1, 256, 0, stream>>>(x, gmm);
    k_consts<<<1,    64, 0, stream>>>(gmm, ab);
    k_pass2 <<<NB2, 256, 0, stream>>>(x, ab, out);
}

// Round 5
// 131.757 us; speedup vs baseline: 2.0867x; 1.2915x over previous
//
#include <hip/hip_runtime.h>

#define HW 50176            // 224*224
#define TT 64
#define NB1 1568            // 8 b × 4 t-chunks × 49 hw-blocks (49*256*4 = HW)
#define NB2 1568            // fallback direct pass2
#define NB3 26656           // 8 b × 68 t × 49 hw-blocks
#define SUMW 0.9999f        // 0.2989+0.587+0.114

__device__ __forceinline__ float gelu_erf(float x) {
    return 0.5f * x * (1.0f + erff(0.70710678f * x));
}
__device__ __forceinline__ float fast_rcp(float v) {
    float r; asm("v_rcp_f32 %0, %1" : "=v"(r) : "v"(v)); return r;
}
__device__ __forceinline__ float gelu_fast(float x) {
    // tanh-form gelu == x*sigmoid(1.59577(x+0.044715x^3)*2); max |err| ~3e-3 vs erf form
    float x2 = x * x;
    float e = exp2f(-x * fmaf(0.1029433f, x2, 2.3022078f));
    return x * fast_rcp(1.0f + e);
}
// order-preserving float <-> uint encoding for atomicMin/Max
__device__ __forceinline__ unsigned encf(float f) {
    unsigned u = __float_as_uint(f);
    return (u & 0x80000000u) ? ~u : (u | 0x80000000u);
}
__device__ __forceinline__ float decf(unsigned u) {
    unsigned b = (u & 0x80000000u) ? (u ^ 0x80000000u) : ~u;
    return __uint_as_float(b);
}
__device__ __forceinline__ unsigned pk_min_f16(unsigned a, unsigned b) {
    unsigned r; asm("v_pk_min_f16 %0, %1, %2" : "=v"(r) : "v"(a), "v"(b)); return r;
}
__device__ __forceinline__ unsigned pack2(float lo, float hi) {
    auto p = __builtin_amdgcn_cvt_pkrtz(lo, hi);
    return __builtin_bit_cast(unsigned, p);
}
__device__ __forceinline__ unsigned min4(float4 re) {
    return pk_min_f16(pk_min_f16(pack2(re.x, -re.x), pack2(re.y, -re.y)),
                      pk_min_f16(pack2(re.z, -re.z), pack2(re.w, -re.w)));
}
__device__ __forceinline__ float4 re_full(float4 w0, float4 w1, float4 w3, float4 w4) {
    float4 r;
    r.x = fmaf(4.f, w4.x - w0.x, 2.f * (w3.x - w1.x));
    r.y = fmaf(4.f, w4.y - w0.y, 2.f * (w3.y - w1.y));
    r.z = fmaf(4.f, w4.z - w0.z, 2.f * (w3.z - w1.z));
    r.w = fmaf(4.f, w4.w - w0.w, 2.f * (w3.w - w1.w));
    return r;
}

__global__ void k_init(unsigned* __restrict__ g) {
    int i = threadIdx.x;           // 128 threads
    g[i] = (i < TT) ? 0xFFFFFFFFu : 0u;
}

// Pass 1 (fused): per-thread 16-window t-chunk over all 3 channels.
// Tracks packed-f16 (min re, min -re) per t AND writes gs = sum_c w_c*gelu(re_c) as f16.
template<bool WGS>
__global__ __launch_bounds__(256, 4) void k_pass1(const float* __restrict__ x,
                                                  unsigned* __restrict__ gmm,
                                                  unsigned short* __restrict__ gs) {
    __shared__ unsigned smin[16], smax[16];
    const int tid = threadIdx.x;
    if (tid < 16) { smin[tid] = 0xFFFFFFFFu; smax[tid] = 0u; }
    __syncthreads();

    const int bid   = blockIdx.x;
    const int b     = bid / 196;
    const int rem   = bid - b * 196;
    const int tc    = rem / 49;            // t-chunk 0..3
    const int hwblk = rem - tc * 49;
    const int t0    = tc * 16;
    const int hw    = (hwblk * 256 + tid) * 4;
    const float* xa = x + ((size_t)(b * 3 + 0) * TT + t0) * (size_t)HW + hw;
    const float* xb = x + ((size_t)(b * 3 + 1) * TT + t0) * (size_t)HW + hw;
    const float* xc = x + ((size_t)(b * 3 + 2) * TT + t0) * (size_t)HW + hw;
    unsigned short* gp = gs + ((size_t)b * TT + t0) * (size_t)HW + hw;

    unsigned acc[16];
    #pragma unroll
    for (int j = 0; j < 16; ++j) acc[j] = 0x7BFF7BFFu;   // (65504, 65504)

    #define LDA(f) (*(const float4*)(xa + (size_t)(f) * HW))
    #define LDB(f) (*(const float4*)(xb + (size_t)(f) * HW))
    #define LDC(f) (*(const float4*)(xc + (size_t)(f) * HW))

    auto step = [&](float4 ra, float4 rb, float4 rc, int j) {
        unsigned m = pk_min_f16(pk_min_f16(min4(ra), min4(rb)), min4(rc));
        acc[j] = pk_min_f16(acc[j], m);
        if constexpr (WGS) {
            float4 g;
            g.x = fmaf(0.114f, gelu_fast(rc.x), fmaf(0.587f, gelu_fast(rb.x), 0.2989f * gelu_fast(ra.x)));
            g.y = fmaf(0.114f, gelu_fast(rc.y), fmaf(0.587f, gelu_fast(rb.y), 0.2989f * gelu_fast(ra.y)));
            g.z = fmaf(0.114f, gelu_fast(rc.z), fmaf(0.587f, gelu_fast(rb.z), 0.2989f * gelu_fast(ra.z)));
            g.w = fmaf(0.114f, gelu_fast(rc.w), fmaf(0.587f, gelu_fast(rb.w), 0.2989f * gelu_fast(ra.w)));
            uint2 st; st.x = pack2(g.x, g.y); st.y = pack2(g.z, g.w);
            *(uint2*)(gp + (size_t)j * HW) = st;
        }
    };

    float4 a0 = LDA(0), a1 = LDA(1), a2 = LDA(2), a3 = LDA(3), a4 = LDA(4), pa = LDA(5);
    float4 b0 = LDB(0), b1 = LDB(1), b2 = LDB(2), b3 = LDB(3), b4 = LDB(4), pb = LDB(5);
    float4 c0 = LDC(0), c1 = LDC(1), c2 = LDC(2), c3 = LDC(3), c4 = LDC(4), pc = LDC(5);

    if (tc < 3) {
        #pragma unroll
        for (int j = 0; j < 16; ++j) {     // windows t0+j, all full-weight
            step(re_full(a0, a1, a3, a4), re_full(b0, b1, b3, b4), re_full(c0, c1, c3, c4), j);
            a0 = a1; a1 = a2; a2 = a3; a3 = a4; a4 = pa;
            b0 = b1; b1 = b2; b2 = b3; b3 = b4; b4 = pb;
            c0 = c1; c1 = c2; c2 = c3; c3 = c4; c4 = pc;
            if (j < 14) { pa = LDA(j + 6); pb = LDB(j + 6); pc = LDC(j + 6); }
        }
    } else {
        #pragma unroll
        for (int j = 0; j < 16; ++j) {     // windows 48+j; tails at 60..63
            float4 ra, rb, rc;
            if (j < 12) {
                ra = re_full(a0, a1, a3, a4); rb = re_full(b0, b1, b3, b4); rc = re_full(c0, c1, c3, c4);
            } else if (j == 12) {          // t=60: weights -3,-1,1,3
                ra.x = fmaf(3.f, a3.x - a0.x, a2.x - a1.x); ra.y = fmaf(3.f, a3.y - a0.y, a2.y - a1.y);
                ra.z = fmaf(3.f, a3.z - a0.z, a2.z - a1.z); ra.w = fmaf(3.f, a3.w - a0.w, a2.w - a1.w);
                rb.x = fmaf(3.f, b3.x - b0.x, b2.x - b1.x); rb.y = fmaf(3.f, b3.y - b0.y, b2.y - b1.y);
                rb.z = fmaf(3.f, b3.z - b0.z, b2.z - b1.z); rb.w = fmaf(3.f, b3.w - b0.w, b2.w - b1.w);
                rc.x = fmaf(3.f, c3.x - c0.x, c2.x - c1.x); rc.y = fmaf(3.f, c3.y - c0.y, c2.y - c1.y);
                rc.z = fmaf(3.f, c3.z - c0.z, c2.z - c1.z); rc.w = fmaf(3.f, c3.w - c0.w, c2.w - c1.w);
            } else if (j == 13) {          // t=61: -2,0,2
                ra.x = 2.f*(a2.x-a0.x); ra.y = 2.f*(a2.y-a0.y); ra.z = 2.f*(a2.z-a0.z); ra.w = 2.f*(a2.w-a0.w);
                rb.x = 2.f*(b2.x-b0.x); rb.y = 2.f*(b2.y-b0.y); rb.z = 2.f*(b2.z-b0.z); rb.w = 2.f*(b2.w-b0.w);
                rc.x = 2.f*(c2.x-c0.x); rc.y = 2.f*(c2.y-c0.y); rc.z = 2.f*(c2.z-c0.z); rc.w = 2.f*(c2.w-c0.w);
            } else if (j == 14) {          // t=62: -1,1
                ra.x = a1.x-a0.x; ra.y = a1.y-a0.y; ra.z = a1.z-a0.z; ra.w = a1.w-a0.w;
                rb.x = b1.x-b0.x; rb.y = b1.y-b0.y; rb.z = b1.z-b0.z; rb.w = b1.w-b0.w;
                rc.x = c1.x-c0.x; rc.y = c1.y-c0.y; rc.z = c1.z-c0.z; rc.w = c1.w-c0.w;
            } else {                       // t=63: weight 0
                ra.x=ra.y=ra.z=ra.w=0.f; rb=ra; rc=ra;
            }
            step(ra, rb, rc, j);
            a0 = a1; a1 = a2; a2 = a3; a3 = a4; a4 = pa;
            b0 = b1; b1 = b2; b2 = b3; b3 = b4; b4 = pb;
            c0 = c1; c1 = c2; c2 = c3; c3 = c4; c4 = pc;
            if (j < 10) { pa = LDA(j + 6); pb = LDB(j + 6); pc = LDC(j + 6); }
        }
    }
    #undef LDA
    #undef LDB
    #undef LDC

    // wave butterfly reduce; lane j keeps window t0+j
    const int lane = tid & 63;
    unsigned keep = 0x7BFF7BFFu;
    #pragma unroll
    for (int j = 0; j < 16; ++j) {
        unsigned a = acc[j];
        #pragma unroll
        for (int off = 32; off; off >>= 1)
            a = pk_min_f16(a, (unsigned)__shfl_xor((int)a, off, 64));
        if (lane == j) keep = a;
    }

    if (lane < 16) {
        union { unsigned u; _Float16 h[2]; } cv; cv.u = keep;
        const float amin = (float)cv.h[0];
        const float amax = -(float)cv.h[1];
        const float g0 = gelu_erf(amin), g1 = gelu_erf(amax);
        const float gmax = fmaxf(g0, g1);
        const float XSTAR = -0.7517916f;             // argmin of gelu
        float gmin;
        if (amin >= XSTAR)      gmin = g0;
        else if (amax <= XSTAR) gmin = g1;
        else                    gmin = fminf(gelu_erf(XSTAR), fminf(g0, g1));
        atomicMin(&smin[lane], encf(gmin));
        atomicMax(&smax[lane], encf(gmax));
    }
    __syncthreads();
    if (tid < 16)            atomicMin(&gmm[t0 + tid], smin[tid]);
    else if (tid < 32)       atomicMax(&gmm[TT + t0 + tid - 16], smax[tid - 16]);
}

__global__ void k_consts(const unsigned* __restrict__ gmm, float* __restrict__ ab) {
    int t = threadIdx.x;                       // 64 threads
    float mn = decf(gmm[t]);
    float mx = decf(gmm[TT + t]) - mn;
    float inv = 1.0f / ((mx != 0.0f) ? mx : 1e-5f);
    ab[t]      = inv;                          // A[t]
    ab[TT + t] = -mn * SUMW * inv;             // B[t]
}

// Pass 3: out[b,t,:] = (t<4) ? 0 : fma(gs[b,t-4,:], A[t-4], B[t-4])
__global__ __launch_bounds__(256) void k_pass3(const unsigned short* __restrict__ gs,
                                               const float* __restrict__ ab,
                                               float* __restrict__ out) {
    const int bid = blockIdx.x;
    const int b  = bid / (68 * 49);
    const int r  = bid - b * (68 * 49);
    const int t  = r / 49;
    const int hb = r - t * 49;
    const int px = (hb * 256 + threadIdx.x) * 4;
    float* op = out + ((size_t)b * 68 + t) * (size_t)HW + px;
    if (t < 4) { *(float4*)op = make_float4(0.f, 0.f, 0.f, 0.f); return; }
    const int tm = t - 4;
    uint2 v = *(const uint2*)(gs + ((size_t)b * TT + tm) * (size_t)HW + px);
    const float A = ab[tm], Bv = ab[TT + tm];
    union { unsigned u; _Float16 h[2]; } lo, hi; lo.u = v.x; hi.u = v.y;
    float4 o;
    o.x = fmaf((float)lo.h[0], A, Bv);
    o.y = fmaf((float)lo.h[1], A, Bv);
    o.z = fmaf((float)hi.h[0], A, Bv);
    o.w = fmaf((float)hi.h[1], A, Bv);
    *(float4*)op = o;
}

// Fallback (ws too small for gs): direct erf pass over x (round-4 pass2)
__global__ __launch_bounds__(256) void k_pass2_direct(const float* __restrict__ x,
                                                      const float* __restrict__ ab,
                                                      float* __restrict__ out) {
    __shared__ float sA[TT], sB[TT];
    const int tid = threadIdx.x;
    if (tid < TT)          sA[tid] = ab[tid];
    else if (tid < 2 * TT) sB[tid - TT] = ab[tid];
    __syncthreads();

    const int pix = blockIdx.x * 256 + tid;    // < 401408 = 8*HW
    const int b  = pix / HW;
    const int hw = pix - b * HW;
    const float* x0 = x + (size_t)(b * 3) * (TT * (size_t)HW) + hw;
    const float* x1 = x0 + (size_t)TT * HW;
    const float* x2 = x1 + (size_t)TT * HW;
    float* op = out + (size_t)b * (68 * (size_t)HW) + hw;

    op[0] = 0.f; op[HW] = 0.f; op[2 * (size_t)HW] = 0.f; op[3 * (size_t)HW] = 0.f;
    op += 4 * (size_t)HW;

    float a0 = x0[0], a1 = x0[HW], a2 = x0[2*HW], a3 = x0[3*HW], a4 = x0[4*HW];
    float b0 = x1[0], b1 = x1[HW], b2 = x1[2*HW], b3 = x1[3*HW], b4 = x1[4*HW];
    float c0 = x2[0], c1 = x2[HW], c2 = x2[2*HW], c3 = x2[3*HW], c4 = x2[4*HW];

    auto emit = [&](int t, float ra, float rb, float rc) {
        float gsv = 0.2989f * gelu_erf(ra) + 0.587f * gelu_erf(rb) + 0.114f * gelu_erf(rc);
        op[(size_t)t * HW] = fmaf(gsv, sA[t], sB[t]);
    };

    for (int t = 0; t < 59; ++t) {
        emit(t, 4.f*(a4-a0) + 2.f*(a3-a1), 4.f*(b4-b0) + 2.f*(b3-b1), 4.f*(c4-c0) + 2.f*(c3-c1));
        a0=a1; a1=a2; a2=a3; a3=a4; a4 = x0[(size_t)(t+5)*HW];
        b0=b1; b1=b2; b2=b3; b3=b4; b4 = x1[(size_t)(t+5)*HW];
        c0=c1; c1=c2; c2=c3; c3=c4; c4 = x2[(size_t)(t+5)*HW];
    }
    emit(59, 4.f*(a4-a0) + 2.f*(a3-a1), 4.f*(b4-b0) + 2.f*(b3-b1), 4.f*(c4-c0) + 2.f*(c3-c1));
    a0=a1; a1=a2; a2=a3; a3=a4; b0=b1; b1=b2; b2=b3; b3=b4; c0=c1; c1=c2; c2=c3; c3=c4;
    emit(60, 3.f*(a3-a0) + (a2-a1), 3.f*(b3-b0) + (b2-b1), 3.f*(c3-c0) + (c2-c1));
    a0=a1; a1=a2; a2=a3; b0=b1; b1=b2; b2=b3; c0=c1; c1=c2; c2=c3;
    emit(61, 2.f*(a2-a0), 2.f*(b2-b0), 2.f*(c2-c0));
    a0=a1; a1=a2; b0=b1; b1=b2; c0=c1; c1=c2;
    emit(62, a1-a0, b1-b0, c1-c0);
    op[63 * (size_t)HW] = sB[63];
}

extern "C" void kernel_launch(void* const* d_in, const int* in_sizes, int n_in,
                              void* d_out, int out_size, void* d_ws, size_t ws_size,
                              hipStream_t stream) {
    const float* x = (const float*)d_in[0];
    float* out = (float*)d_out;
    unsigned* gmm = (unsigned*)d_ws;                       // 128 u32
    float* ab = (float*)d_ws + 128;                        // 128 f32
    unsigned short* gs = (unsigned short*)((char*)d_ws + 1024);
    const size_t need = 1024 + (size_t)8 * TT * (size_t)HW * 2;   // ~51.4 MB

    k_init<<<1, 128, 0, stream>>>(gmm);
    if (ws_size >= need) {
        k_pass1<true><<<NB1, 256, 0, stream>>>(x, gmm, gs);
        k_consts<<<1, 64, 0, stream>>>(gmm, ab);
        k_pass3<<<NB3, 256, 0, stream>>>(gs, ab, out);
    } else {
        k_pass1<false><<<NB1, 256, 0, stream>>>(x, gmm, nullptr);
        k_consts<<<1, 64, 0, stream>>>(gmm, ab);
        k_pass2_direct<<<NB2, 256, 0, stream>>>(x, ab, out);
    }
}